// Round 2
// baseline (5747.726 us; speedup 1.0000x reference)
//
#include <hip/hip_runtime.h>

#define BB 64
#define TT 4995
#define VV 4096
#define EE 100
#define UU 64
#define U3 192

// Static device workspace: embW[v][k] = (emb @ W1 + b1[0])[v][k], 3.07 MB.
// Static so we don't depend on ws_size being >= 3.1 MB; recomputed every
// launch (same work every call — graph-capture safe).
__device__ float g_embW[VV * U3];

__device__ __forceinline__ float fast_sigmoid(float x) {
    // 1/(1+e^-x); v_exp + v_rcp, ~1ulp each — plenty for 1e-2 threshold
    return __builtin_amdgcn_rcpf(1.0f + __expf(-x));
}
__device__ __forceinline__ float fast_tanh(float x) {
    // tanh(x) = 2*sigmoid(2x) - 1; saturates correctly for large |x|
    return __builtin_amdgcn_rcpf(1.0f + __expf(-2.0f * x)) * 2.0f - 1.0f;
}

// Kernel A: embW[v][k] = sum_j emb[v][j] * W1[j][k] + b1[0][k]
// Folds the embedding gather + input projection into a 3 MB L2-resident table.
__global__ void gru_embw_kernel(const float* __restrict__ emb,
                                const float* __restrict__ W1,
                                const float* __restrict__ b1) {
    __shared__ float row[EE];
    const int v = blockIdx.x;
    const int k = threadIdx.x;  // 0..191
    if (k < EE) row[k] = emb[v * EE + k];
    __syncthreads();
    float acc = b1[k];  // b1 row 0 (input bias)
    #pragma unroll 4
    for (int j = 0; j < EE; ++j)
        acc = fmaf(row[j], W1[j * U3 + k], acc);
    g_embW[v * U3 + k] = acc;
}

// Kernel B: fused 2-layer GRU scan, one workgroup per batch element.
// Thread k holds column k of U1, W2, U2 in registers.
__global__ __launch_bounds__(192, 1)
void gru_scan_kernel(const int* __restrict__ tokens,
                     const float* __restrict__ U1,
                     const float* __restrict__ b1,
                     const float* __restrict__ W2,
                     const float* __restrict__ U2,
                     const float* __restrict__ b2,
                     const float* __restrict__ Wout,
                     const float* __restrict__ bout,
                     float* __restrict__ out) {
    const int b = blockIdx.x;
    const int k = threadIdx.x;  // 0..191

    __shared__ __align__(16) float h1[UU];
    __shared__ __align__(16) float h2[UU];
    __shared__ float g_z[UU], g_r[UU], g_xh[UU], g_hph[UU];

    // Per-thread weight columns (one-time loads; matrices are L2-resident)
    float u1c[UU], w2c[UU], u2c[UU];
    #pragma unroll
    for (int j = 0; j < UU; ++j) {
        u1c[j] = U1[j * U3 + k];
        w2c[j] = W2[j * U3 + k];
        u2c[j] = U2[j * U3 + k];
    }
    const float bu1 = b1[U3 + k];   // b1 row 1 (recurrent bias)
    const float b20 = b2[k];        // b2 row 0
    const float b21 = b2[U3 + k];   // b2 row 1

    if (k < UU) { h1[k] = 0.0f; h2[k] = 0.0f; }
    __syncthreads();

    const int* tokb = tokens + b * TT;
    int tok1 = tokb[1];
    float xk = g_embW[(long)tokb[0] * U3 + k];  // xp1 for t=0 (bias folded in)

    for (int t = 0; t < TT; ++t) {
        // ---- prefetch next step's token + embW row (hides L2 latency) ----
        const int tnn = (t + 2 < TT) ? (t + 2) : (TT - 1);
        const int tok_nn = tokb[tnn];
        const float xk_next = g_embW[(long)tok1 * U3 + k];

        // ---- layer 1: hp1[k] = dot(h1, U1[:,k]) + b1[1][k] ----
        float hr[UU];
        #pragma unroll
        for (int j4 = 0; j4 < UU / 4; ++j4) {
            const float4 v4 = ((const float4*)h1)[j4];  // broadcast LDS read
            hr[4 * j4 + 0] = v4.x; hr[4 * j4 + 1] = v4.y;
            hr[4 * j4 + 2] = v4.z; hr[4 * j4 + 3] = v4.w;
        }
        float acc = bu1;
        #pragma unroll
        for (int j = 0; j < UU; ++j) acc = fmaf(hr[j], u1c[j], acc);

        if (k < UU)            g_z[k]       = fast_sigmoid(xk + acc);
        else if (k < 2 * UU)   g_r[k - UU]  = fast_sigmoid(xk + acc);
        else { g_xh[k - 2 * UU] = xk; g_hph[k - 2 * UU] = acc; }
        __syncthreads();

        if (k < UU) {
            const float z = g_z[k];
            const float hh = fast_tanh(g_xh[k] + g_r[k] * g_hph[k]);
            h1[k] = z * h1[k] + (1.0f - z) * hh;
        }
        __syncthreads();

        // ---- layer 2: xp2[k] = dot(h1new, W2[:,k]) + b2[0][k]
        //               hp2[k] = dot(h2,    U2[:,k]) + b2[1][k] ----
        float h1r[UU], h2r[UU];
        #pragma unroll
        for (int j4 = 0; j4 < UU / 4; ++j4) {
            const float4 a4 = ((const float4*)h1)[j4];
            const float4 c4 = ((const float4*)h2)[j4];
            h1r[4 * j4 + 0] = a4.x; h1r[4 * j4 + 1] = a4.y;
            h1r[4 * j4 + 2] = a4.z; h1r[4 * j4 + 3] = a4.w;
            h2r[4 * j4 + 0] = c4.x; h2r[4 * j4 + 1] = c4.y;
            h2r[4 * j4 + 2] = c4.z; h2r[4 * j4 + 3] = c4.w;
        }
        float a1 = b20, a2 = b21;
        #pragma unroll
        for (int j = 0; j < UU; ++j) {
            a1 = fmaf(h1r[j], w2c[j], a1);
            a2 = fmaf(h2r[j], u2c[j], a2);
        }

        if (k < UU)            g_z[k]       = fast_sigmoid(a1 + a2);
        else if (k < 2 * UU)   g_r[k - UU]  = fast_sigmoid(a1 + a2);
        else { g_xh[k - 2 * UU] = a1; g_hph[k - 2 * UU] = a2; }
        __syncthreads();

        if (k < UU) {
            const float z = g_z[k];
            const float hh = fast_tanh(g_xh[k] + g_r[k] * g_hph[k]);
            h2[k] = z * h2[k] + (1.0f - z) * hh;
        }
        __syncthreads();

        // rotate prefetch pipeline
        xk = xk_next;
        tok1 = tok_nn;
    }

    // ---- output head: out[b] = sigmoid(dot(h2, Wout) + bout) ----
    if (k == 0) {
        float s = 0.0f;
        #pragma unroll 4
        for (int j = 0; j < UU; ++j) s = fmaf(h2[j], Wout[j], s);
        out[b] = fast_sigmoid(s + bout[0]);
    }
}

extern "C" void kernel_launch(void* const* d_in, const int* in_sizes, int n_in,
                              void* d_out, int out_size, void* d_ws, size_t ws_size,
                              hipStream_t stream) {
    const int*   tokens = (const int*)  d_in[0];
    const float* emb    = (const float*)d_in[1];
    const float* W1     = (const float*)d_in[2];
    const float* U1w    = (const float*)d_in[3];
    const float* b1     = (const float*)d_in[4];
    const float* W2     = (const float*)d_in[5];
    const float* U2w    = (const float*)d_in[6];
    const float* b2     = (const float*)d_in[7];
    const float* Wout   = (const float*)d_in[8];
    const float* bout   = (const float*)d_in[9];
    float* out = (float*)d_out;

    gru_embw_kernel<<<VV, 192, 0, stream>>>(emb, W1, b1);
    gru_scan_kernel<<<BB, 192, 0, stream>>>(tokens, U1w, b1, W2, U2w,
                                            b2, Wout, bout, out);
}